// Round 2
// baseline (83.556 us; speedup 1.0000x reference)
//
#include <hip/hip_runtime.h>

#define BS 16384
#define D  512
#define MARGIN 1.0f

#define RPW 2                  // rows per wave: LOW VGPR -> HIGH occupancy
#define WPB 4                  // waves per block (256 threads)
#define RPB (RPW * WPB)        // 8 rows per block
#define NBLK (BS / RPB)        // 2048 blocks -> up to 7 blocks/CU resident

// Stage 1, occupancy experiment: same total in-flight bytes per CU as the
// RPW=8 version (~300 KB) but spread over 28 waves/CU instead of 8.
// RPW=2 -> 12 float4 in flight (48 VGPRs data); all loads share two
// lane-offset VGPRs (sgpr row base + voffset form), target ~64-72 VGPR.
// __launch_bounds__(256, 7): min 7 waves/EU -> allocator capped ~73 VGPR,
// 7 blocks/CU. If latency x wave-count is the binding constraint this is
// ~2x on stage 1; if neutral, the ceiling is fixed overhead / miss-queue.
__global__ __launch_bounds__(256, 7) void triplet_partial(
    const float* __restrict__ batch,
    const int*   __restrict__ triplets,
    float* __restrict__ partial)
{
    const int lane = threadIdx.x & 63;
    const int wib  = threadIdx.x >> 6;
    const int rowBase = (blockIdx.x * WPB + wib) * RPW;

    __shared__ float s_part[WPB];

    // (1) indices: 2 rows x 3 = 6 contiguous ints, wave-uniform -> s_load
    int t0[RPW], t1[RPW], t2[RPW];
    #pragma unroll
    for (int r = 0; r < RPW; ++r) {
        t0[r] = triplets[(rowBase + r) * 3 + 0];
        t1[r] = triplets[(rowBase + r) * 3 + 1];
        t2[r] = triplets[(rowBase + r) * 3 + 2];
    }

    // (2) issue all loads: 2 rows x 3 ptrs x 2 chunks = 12 float4.
    // All 12 share the same two voffsets (lane, lane+64) against uniform
    // sgpr row bases -> minimal address VGPRs.
    float4 av[RPW][2], pv[RPW][2], nv[RPW][2];
    #pragma unroll
    for (int r = 0; r < RPW; ++r) {
        const float4* __restrict__ a = (const float4*)(batch + (size_t)t0[r] * D);
        const float4* __restrict__ p = (const float4*)(batch + (size_t)t1[r] * D);
        const float4* __restrict__ n = (const float4*)(batch + (size_t)t2[r] * D);
        #pragma unroll
        for (int k = 0; k < 2; ++k) {
            const int j = lane + 64 * k;     // D/4 = 128 float4 per row
            av[r][k] = a[j];
            pv[r][k] = p[j];
            nv[r][k] = n[j];
        }
    }

    // (3) per-lane partials: sum((a-p)^2 - (a-n)^2), one acc per row
    float acc[RPW];
    #pragma unroll
    for (int r = 0; r < RPW; ++r) {
        float s = 0.0f;
        #pragma unroll
        for (int k = 0; k < 2; ++k) {
            float dp, dn;
            dp = av[r][k].x - pv[r][k].x; dn = av[r][k].x - nv[r][k].x; s += dp * dp - dn * dn;
            dp = av[r][k].y - pv[r][k].y; dn = av[r][k].y - nv[r][k].y; s += dp * dp - dn * dn;
            dp = av[r][k].z - pv[r][k].z; dn = av[r][k].z - nv[r][k].z; s += dp * dp - dn * dn;
            dp = av[r][k].w - pv[r][k].w; dn = av[r][k].w - nv[r][k].w; s += dp * dp - dn * dn;
        }
        acc[r] = s;
    }

    // (4) interleaved wave reductions: 2 independent cross-lane chains/level
    #pragma unroll
    for (int off = 32; off > 0; off >>= 1) {
        #pragma unroll
        for (int r = 0; r < RPW; ++r)
            acc[r] += __shfl_down(acc[r], off, 64);
    }

    if (lane == 0) {
        float waveLoss = 0.0f;
        #pragma unroll
        for (int r = 0; r < RPW; ++r) {
            const float loss = acc[r] + MARGIN;
            waveLoss += (loss > 0.0f) ? loss : 0.0f;
        }
        s_part[wib] = waveLoss;
    }
    __syncthreads();
    if (threadIdx.x == 0)
        partial[blockIdx.x] = s_part[0] + s_part[1] + s_part[2] + s_part[3];
}

// Stage 2: reduce NBLK=2048 partials -> out[0]. One block, deterministic.
__global__ __launch_bounds__(256) void triplet_reduce(
    const float* __restrict__ partial,
    float* __restrict__ out)
{
    const int lane = threadIdx.x & 63;
    const int wib  = threadIdx.x >> 6;

    // 2048 floats = 512 float4: each thread reads 2
    const float4* p4 = (const float4*)partial;
    const float4 a = p4[threadIdx.x];
    const float4 b = p4[threadIdx.x + 256];
    float acc = (a.x + a.y + a.z + a.w) + (b.x + b.y + b.z + b.w);

    #pragma unroll
    for (int off = 32; off > 0; off >>= 1)
        acc += __shfl_down(acc, off, 64);

    __shared__ float s[4];
    if (lane == 0) s[wib] = acc;
    __syncthreads();
    if (threadIdx.x == 0)
        out[0] = s[0] + s[1] + s[2] + s[3];
}

extern "C" void kernel_launch(void* const* d_in, const int* in_sizes, int n_in,
                              void* d_out, int out_size, void* d_ws, size_t ws_size,
                              hipStream_t stream) {
    const float* batch    = (const float*)d_in[0];
    const int*   triplets = (const int*)d_in[1];
    float*       out      = (float*)d_out;
    float*       partial  = (float*)d_ws;    // NBLK floats = 8 KB scratch

    triplet_partial<<<NBLK, 256, 0, stream>>>(batch, triplets, partial);
    triplet_reduce<<<1, 256, 0, stream>>>(partial, out);
}